// Round 2
// baseline (381.893 us; speedup 1.0000x reference)
//
#include <hip/hip_runtime.h>
#include <hip/hip_bf16.h>

typedef unsigned short u16;
typedef __bf16 bf16x8 __attribute__((ext_vector_type(8)));
typedef float f32x4 __attribute__((ext_vector_type(4)));

#define MFMA16(a, b, c) __builtin_amdgcn_mfma_f32_16x16x32_bf16(a, b, c, 0, 0, 0)

#define EMB 1024
#define SEQ 2048
#define NH 16
#define HD 64

__device__ __forceinline__ u16 f2b(float f) {
    __hip_bfloat16 h = __float2bfloat16(f);
    return *reinterpret_cast<u16*>(&h);
}
__device__ __forceinline__ bf16x8 ldfrag(const u16* p) {
    return *reinterpret_cast<const bf16x8*>(p);
}
// load 8 fp32, round-to-nearest to bf16x8
__device__ __forceinline__ bf16x8 cvt8(const float* p) {
    const float4 a = *reinterpret_cast<const float4*>(p);
    const float4 b = *reinterpret_cast<const float4*>(p + 4);
    union { bf16x8 v; u16 u[8]; } r;
    r.u[0] = f2b(a.x); r.u[1] = f2b(a.y); r.u[2] = f2b(a.z); r.u[3] = f2b(a.w);
    r.u[4] = f2b(b.x); r.u[5] = f2b(b.y); r.u[6] = f2b(b.z); r.u[7] = f2b(b.w);
    return r.v;
}

// ---------------------------------------------------------------------------
// GEMM: C = A(MxK) @ W(NxK)^T + bias, 128x128 tile, BK=32, 256 thr (4 waves).
// A is fp32 (AF32=true) or bf16 workspace (false); W/bias always fp32 inputs.
// mode 0: Q epilogue -> Qa[:,0:64]=Q/8, Qa[:,64:128]=lam*tanh(Q)   (B,H,S,128)
// mode 1: K epilogue -> Ka[:,0:64]=K, TK=tanh(K)                    (B,H,S,*)
// mode 2: V epilogue -> Vb=V                                        (B,H,S,64)
// mode 3: O epilogue -> out = val fp32 (row-major M x N)
// ---------------------------------------------------------------------------
template<bool AF32>
__global__ __launch_bounds__(256) void gemm_epi(
        const float* __restrict__ Af, const u16* __restrict__ Ab,
        const float* __restrict__ W0, const float* __restrict__ B0,
        const float* __restrict__ W1, const float* __restrict__ B1,
        const float* __restrict__ W2, const float* __restrict__ B2,
        const float* __restrict__ lam,
        u16* __restrict__ Qa, u16* __restrict__ Ka,
        u16* __restrict__ TK, u16* __restrict__ Vb,
        float* __restrict__ out, int modeBase)
{
    const int mode = modeBase + blockIdx.z;
    const float* W; const float* bias;
    if (blockIdx.z == 0)      { W = W0; bias = B0; }
    else if (blockIdx.z == 1) { W = W1; bias = B1; }
    else                      { W = W2; bias = B2; }

    __shared__ __attribute__((aligned(16))) u16 sA[128 * 40];
    __shared__ __attribute__((aligned(16))) u16 sB[128 * 40];

    const int t = threadIdx.x;
    const int w = t >> 6, L = t & 63;
    const int wm = w >> 1, wn = w & 1;
    const int lr = L & 15, lq = L >> 4;
    const int m0 = blockIdx.y * 128, n0 = blockIdx.x * 128;

    f32x4 acc[4][4];
#pragma unroll
    for (int i = 0; i < 4; i++)
#pragma unroll
        for (int j = 0; j < 4; j++) { f32x4 z = {0.f, 0.f, 0.f, 0.f}; acc[i][j] = z; }

    for (int k0 = 0; k0 < EMB; k0 += 32) {
        __syncthreads();
#pragma unroll
        for (int i = 0; i < 2; i++) {
            int c = t + 256 * i;                 // 512 chunks of 8 elems
            int row = c >> 2, col = (c & 3) * 8;
            if constexpr (AF32)
                *(bf16x8*)&sA[row * 40 + col] = cvt8(&Af[(size_t)(m0 + row) * EMB + k0 + col]);
            else
                *(bf16x8*)&sA[row * 40 + col] = ldfrag(&Ab[(size_t)(m0 + row) * EMB + k0 + col]);
            *(bf16x8*)&sB[row * 40 + col] = cvt8(&W[(size_t)(n0 + row) * EMB + k0 + col]);
        }
        __syncthreads();
        bf16x8 af[4], bfr[4];
#pragma unroll
        for (int mi = 0; mi < 4; mi++) af[mi]  = ldfrag(&sA[(wm * 64 + mi * 16 + lr) * 40 + lq * 8]);
#pragma unroll
        for (int ni = 0; ni < 4; ni++) bfr[ni] = ldfrag(&sB[(wn * 64 + ni * 16 + lr) * 40 + lq * 8]);
#pragma unroll
        for (int mi = 0; mi < 4; mi++)
#pragma unroll
            for (int ni = 0; ni < 4; ni++)
                acc[mi][ni] = MFMA16(af[mi], bfr[ni], acc[mi][ni]);
    }

    const float lamf = lam[0];
#pragma unroll
    for (int mi = 0; mi < 4; mi++)
#pragma unroll
        for (int ni = 0; ni < 4; ni++)
#pragma unroll
            for (int r = 0; r < 4; r++) {
                int m = m0 + wm * 64 + mi * 16 + lq * 4 + r;
                int n = n0 + wn * 64 + ni * 16 + lr;
                float val = acc[mi][ni][r] + bias[n];
                if (mode == 3) {
                    out[(size_t)m * EMB + n] = val;
                } else {
                    int b = m >> 11, s = m & 2047;
                    int h = n >> 6,  d = n & 63;
                    size_t i64  = ((size_t)(b * NH + h) * SEQ + s) * HD + d;
                    size_t i128 = ((size_t)(b * NH + h) * SEQ + s) * 128 + d;
                    if (mode == 0) {
                        Qa[i128]      = f2b(val * 0.125f);
                        Qa[i128 + 64] = f2b(lamf * tanhf(val));
                    } else if (mode == 1) {
                        Ka[i128] = f2b(val);
                        TK[i64]  = f2b(tanhf(val));
                    } else {
                        Vb[i64] = f2b(val);
                    }
                }
            }
}

// ---------------------------------------------------------------------------
// U kernel: Ka[:,64:128] = TK(S x 64) @ J_h(64 x 64)^T  per (b,h)
// grid: (S/64, B*H), 256 threads (4 waves x 16-row strips)
// ---------------------------------------------------------------------------
__global__ __launch_bounds__(256) void ukern(
        const u16* __restrict__ TK, const float* __restrict__ J,
        u16* __restrict__ Ka)
{
    __shared__ __attribute__((aligned(16))) u16 sJ[64 * 72];
    const int t = threadIdx.x, w = t >> 6, L = t & 63, lr = L & 15, lq = L >> 4;
    const int rt = blockIdx.x, bh = blockIdx.y, h = bh & 15;

#pragma unroll
    for (int i = 0; i < 2; i++) {
        int c = t + 256 * i;                     // 512 chunks of 8 elems
        int row = c >> 3, col = (c & 7) * 8;
        *(bf16x8*)&sJ[row * 72 + col] = cvt8(&J[(size_t)h * 4096 + row * 64 + col]);
    }
    __syncthreads();

    const u16* tkrow = &TK[((size_t)bh * SEQ + rt * 64 + w * 16 + lr) * HD];
    bf16x8 a0 = ldfrag(tkrow + lq * 8);
    bf16x8 a1 = ldfrag(tkrow + lq * 8 + 32);
#pragma unroll
    for (int nt = 0; nt < 4; nt++) {
        f32x4 acc = {0.f, 0.f, 0.f, 0.f};
        acc = MFMA16(a0, ldfrag(&sJ[(nt * 16 + lr) * 72 + lq * 8]), acc);
        acc = MFMA16(a1, ldfrag(&sJ[(nt * 16 + lr) * 72 + lq * 8 + 32]), acc);
#pragma unroll
        for (int r = 0; r < 4; r++) {
            int j = rt * 64 + w * 16 + lq * 4 + r;
            Ka[((size_t)bh * SEQ + j) * 128 + 64 + nt * 16 + lr] = f2b(acc[r]);
        }
    }
}

// ---------------------------------------------------------------------------
// Causal flash attention: Qa(S x 128) @ Ka(S x 128)^T -> online softmax -> @V
// grid: (S/64 q-tiles, B*H), 256 threads. BM=BN=64.
// Output attn (bf16) in (B, S, H, Hd) layout for the final projection GEMM.
// ---------------------------------------------------------------------------
__global__ __launch_bounds__(256) void flash(
        const u16* __restrict__ Qa, const u16* __restrict__ Ka,
        const u16* __restrict__ Vb, u16* __restrict__ attn)
{
    __shared__ __attribute__((aligned(16))) u16 sK[64 * 136];
    __shared__ __attribute__((aligned(16))) u16 sV[64 * 72];   // sV[d][j] = V[j][d]
    __shared__ __attribute__((aligned(16))) u16 sP[4 * 16 * 72];

    const int t = threadIdx.x, w = t >> 6, L = t & 63, lr = L & 15, lq = L >> 4;
    const int qt = blockIdx.x, bh = blockIdx.y;
    const int qm = qt * 64;
    const u16* Qbase = Qa + (size_t)bh * SEQ * 128;
    const u16* Kbase = Ka + (size_t)bh * SEQ * 128;
    const u16* Vbase = Vb + (size_t)bh * SEQ * 64;

    bf16x8 qf[4];
    {
        const u16* qrow = Qbase + (size_t)(qm + w * 16 + lr) * 128;
#pragma unroll
        for (int s = 0; s < 4; s++) qf[s] = ldfrag(qrow + lq * 8 + 32 * s);
    }

    f32x4 O[4];
#pragma unroll
    for (int i = 0; i < 4; i++) { f32x4 z = {0.f, 0.f, 0.f, 0.f}; O[i] = z; }
    float mrun[4], lrun[4];
#pragma unroll
    for (int r = 0; r < 4; r++) { mrun[r] = -INFINITY; lrun[r] = 0.f; }

    for (int kt = 0; kt <= qt; kt++) {
        const int kn = kt * 64;
        __syncthreads();
        // stage K-tile (64 x 128, stride 136)
#pragma unroll
        for (int i = 0; i < 4; i++) {
            int c = t + 256 * i;                 // 1024 chunks of 16B
            int row = c >> 4, col = (c & 15) * 8;
            *(bf16x8*)&sK[row * 136 + col] = ldfrag(&Kbase[(size_t)(kn + row) * 128 + col]);
        }
        // stage V transposed: sV[d][j]
        {
            int j = t >> 2, c0 = (t & 3) * 16;
            bf16x8 v0 = ldfrag(&Vbase[(size_t)(kn + j) * 64 + c0]);
            bf16x8 v1 = ldfrag(&Vbase[(size_t)(kn + j) * 64 + c0 + 8]);
#pragma unroll
            for (int e = 0; e < 8; e++) sV[(c0 + e) * 72 + j]     = ((u16*)&v0)[e];
#pragma unroll
            for (int e = 0; e < 8; e++) sV[(c0 + 8 + e) * 72 + j] = ((u16*)&v1)[e];
        }
        __syncthreads();

        // S-tile = Qa @ Ka^T  (16 rows/wave x 64 cols)
        f32x4 sc[4];
#pragma unroll
        for (int nt = 0; nt < 4; nt++) {
            f32x4 a = {0.f, 0.f, 0.f, 0.f};
#pragma unroll
            for (int s = 0; s < 4; s++)
                a = MFMA16(qf[s], ldfrag(&sK[(nt * 16 + lr) * 136 + lq * 8 + 32 * s]), a);
            sc[nt] = a;
        }
        if (kt == qt) {
#pragma unroll
            for (int nt = 0; nt < 4; nt++)
#pragma unroll
                for (int r = 0; r < 4; r++) {
                    int mq = w * 16 + lq * 4 + r;
                    int nk = nt * 16 + lr;
                    if (nk > mq) sc[nt][r] = -INFINITY;
                }
        }
        // online softmax (rows live in 16-lane groups: shfl_xor 1,2,4,8)
        float mnew[4], alpha[4];
#pragma unroll
        for (int r = 0; r < 4; r++) {
            float mx = fmaxf(fmaxf(sc[0][r], sc[1][r]), fmaxf(sc[2][r], sc[3][r]));
            mx = fmaxf(mx, __shfl_xor(mx, 1));
            mx = fmaxf(mx, __shfl_xor(mx, 2));
            mx = fmaxf(mx, __shfl_xor(mx, 4));
            mx = fmaxf(mx, __shfl_xor(mx, 8));
            mnew[r] = fmaxf(mrun[r], mx);
            alpha[r] = (mrun[r] == -INFINITY) ? 0.f : __expf(mrun[r] - mnew[r]);
        }
#pragma unroll
        for (int nt = 0; nt < 4; nt++)
#pragma unroll
            for (int r = 0; r < 4; r++)
                sc[nt][r] = __expf(sc[nt][r] - mnew[r]);
#pragma unroll
        for (int r = 0; r < 4; r++) {
            float sm = sc[0][r] + sc[1][r] + sc[2][r] + sc[3][r];
            sm += __shfl_xor(sm, 1);
            sm += __shfl_xor(sm, 2);
            sm += __shfl_xor(sm, 4);
            sm += __shfl_xor(sm, 8);
            lrun[r] = lrun[r] * alpha[r] + sm;
            mrun[r] = mnew[r];
        }
#pragma unroll
        for (int nt = 0; nt < 4; nt++)
#pragma unroll
            for (int r = 0; r < 4; r++)
                O[nt][r] *= alpha[r];
        // P (C-layout) -> LDS (row-major, per-wave strip)
#pragma unroll
        for (int nt = 0; nt < 4; nt++)
#pragma unroll
            for (int r = 0; r < 4; r++)
                sP[(w * 16 + lq * 4 + r) * 72 + nt * 16 + lr] = f2b(sc[nt][r]);
        __syncthreads();
        // O += P @ V
#pragma unroll
        for (int s2 = 0; s2 < 2; s2++) {
            bf16x8 pf = ldfrag(&sP[(w * 16 + lr) * 72 + lq * 8 + 32 * s2]);
#pragma unroll
            for (int nt = 0; nt < 4; nt++) {
                bf16x8 vf = ldfrag(&sV[(nt * 16 + lr) * 72 + lq * 8 + 32 * s2]);
                O[nt] = MFMA16(pf, vf, O[nt]);
            }
        }
    }

    const int b = bh >> 4, h = bh & 15;
#pragma unroll
    for (int r = 0; r < 4; r++) {
        float inv = 1.0f / lrun[r];
        int srow = qm + w * 16 + lq * 4 + r;
        size_t base = ((size_t)(b * SEQ + srow) * NH + h) * HD;
#pragma unroll
        for (int nt = 0; nt < 4; nt++)
            attn[base + nt * 16 + lr] = f2b(O[nt][r] * inv);
    }
}

// ---------------------------------------------------------------------------
extern "C" void kernel_launch(void* const* d_in, const int* in_sizes, int n_in,
                              void* d_out, int out_size, void* d_ws, size_t ws_size,
                              hipStream_t stream)
{
    const float* x   = (const float*)d_in[0];
    const float* Wq  = (const float*)d_in[1];
    const float* bq  = (const float*)d_in[2];
    const float* Wk  = (const float*)d_in[3];
    const float* bk  = (const float*)d_in[4];
    const float* Wv  = (const float*)d_in[5];
    const float* bv  = (const float*)d_in[6];
    const float* Wo  = (const float*)d_in[7];
    const float* bo  = (const float*)d_in[8];
    const float* J   = (const float*)d_in[9];
    const float* lam = (const float*)d_in[10];

    u16* ws   = (u16*)d_ws;
    u16* Qa   = ws;                                   // 32*2048*128 bf16
    u16* Ka   = Qa + (size_t)32 * 2048 * 128;         // 32*2048*128 bf16
    u16* TK   = Ka + (size_t)32 * 2048 * 128;         // 32*2048*64  bf16
    u16* Vb   = TK + (size_t)32 * 2048 * 64;          // 32*2048*64  bf16
    u16* attn = Vb + (size_t)32 * 2048 * 64;          // 4096*1024   bf16
    float* dout = (float*)d_out;

    dim3 blk(256);
    // fused Q/K/V projections (z selects weight + epilogue)
    gemm_epi<true><<<dim3(8, 32, 3), blk, 0, stream>>>(
        x, nullptr, Wq, bq, Wk, bk, Wv, bv, lam, Qa, Ka, TK, Vb, dout, 0);
    // Ka[:,64:128] = tanh(K) @ J_h^T
    ukern<<<dim3(32, 32), blk, 0, stream>>>(TK, J, Ka);
    // causal flash attention with augmented 128-dim QK
    flash<<<dim3(32, 32), blk, 0, stream>>>(Qa, Ka, Vb, attn);
    // output projection (A = attn bf16 from workspace)
    gemm_epi<false><<<dim3(8, 32, 1), blk, 0, stream>>>(
        nullptr, attn, Wo, bo, Wo, bo, Wo, bo, lam, Qa, Ka, TK, Vb, dout, 3);
}

// Round 3
// 274.834 us; speedup vs baseline: 1.3895x; 1.3895x over previous
//
#include <hip/hip_runtime.h>
#include <hip/hip_bf16.h>

typedef unsigned short u16;
typedef __bf16 bf16x8 __attribute__((ext_vector_type(8)));
typedef float f32x4 __attribute__((ext_vector_type(4)));
typedef unsigned short u16x4 __attribute__((ext_vector_type(4)));

#define MFMA16(a, b, c) __builtin_amdgcn_mfma_f32_16x16x32_bf16(a, b, c, 0, 0, 0)

#define EMB 1024
#define SEQ 2048
#define NH 16
#define HD 64

// async global->LDS, 16B per lane; LDS dest = wave-uniform base + lane*16
#define GLOAD_LDS16(g, l) __builtin_amdgcn_global_load_lds( \
    (const __attribute__((address_space(1))) unsigned int*)(g), \
    (__attribute__((address_space(3))) unsigned int*)(l), 16, 0, 0)

__device__ __forceinline__ float b2f(u16 u) {
    union { unsigned int i; float f; } v; v.i = ((unsigned int)u) << 16; return v.f;
}
__device__ __forceinline__ u16 f2b(float f) {
    __hip_bfloat16 h = __float2bfloat16(f);
    return *reinterpret_cast<u16*>(&h);
}
__device__ __forceinline__ bf16x8 ldfrag(const u16* p) {
    return *reinterpret_cast<const bf16x8*>(p);
}
__device__ __forceinline__ bf16x8 cvt8(const float* p) {
    const float4 a = *reinterpret_cast<const float4*>(p);
    const float4 b = *reinterpret_cast<const float4*>(p + 4);
    union { bf16x8 v; u16 u[8]; } r;
    r.u[0] = f2b(a.x); r.u[1] = f2b(a.y); r.u[2] = f2b(a.z); r.u[3] = f2b(a.w);
    r.u[4] = f2b(b.x); r.u[5] = f2b(b.y); r.u[6] = f2b(b.z); r.u[7] = f2b(b.w);
    return r.v;
}
__device__ __forceinline__ bf16x8 tanh8(bf16x8 v) {
    union { bf16x8 v; u16 u[8]; } in, out; in.v = v;
#pragma unroll
    for (int e = 0; e < 8; e++) out.u[e] = f2b(tanhf(b2f(in.u[e])));
    return out.v;
}

// ---------------------------------------------------------------------------
// fp32 -> bf16 conversion: [x (4096x1024) | Wq | Wk | Wv | Wo] -> ws bf16
// ---------------------------------------------------------------------------
__global__ __launch_bounds__(256) void cvt_all(
        const float* __restrict__ x,  const float* __restrict__ Wq,
        const float* __restrict__ Wk, const float* __restrict__ Wv,
        const float* __restrict__ Wo, u16* __restrict__ dst)
{
    size_t i = ((size_t)blockIdx.x * 256 + threadIdx.x) * 8;
    const float* src; size_t off;
    if (i < 4194304) { src = x; off = i; }
    else {
        size_t j = i - 4194304; int w = (int)(j >> 20); off = j & 1048575;
        src = (w == 0) ? Wq : (w == 1) ? Wk : (w == 2) ? Wv : Wo;
    }
    *(bf16x8*)&dst[i] = cvt8(src + off);
}

// ---------------------------------------------------------------------------
// GEMM: C = A(MxK,bf16) @ W(NxK,bf16)^T + bias(fp32). Tile MI*32 x 128, BK=32.
// 256 thr = 4 waves (2x2). Staging via global_load_lds + XOR chunk swizzle.
// mode 0: Qa[:,0:64]=Q/8, Qa[:,64:128]=lam*tanh(Q)   (B,H,S,128) bf16
// mode 1: Ka[:,0:64]=K                                (B,H,S,128) bf16
// mode 2: Vt[b,h,d,s]=V  (transposed)                 (B,H,HD,S)  bf16
// mode 3: out = val fp32 (row-major M x EMB)
// ---------------------------------------------------------------------------
template<int MI>   // m-frags per wave (4 -> 128-row tile, 2 -> 64-row tile)
__global__ __launch_bounds__(256) void gemm_epi(
        const u16* __restrict__ A,
        const u16* __restrict__ W0, const float* __restrict__ B0,
        const u16* __restrict__ W1, const float* __restrict__ B1,
        const u16* __restrict__ W2, const float* __restrict__ B2,
        const float* __restrict__ lam,
        u16* __restrict__ Qa, u16* __restrict__ Ka, u16* __restrict__ Vt,
        float* __restrict__ out, int modeBase)
{
    const int mode = modeBase + blockIdx.z;
    const u16* W; const float* bias;
    if (blockIdx.z == 0)      { W = W0; bias = B0; }
    else if (blockIdx.z == 1) { W = W1; bias = B1; }
    else                      { W = W2; bias = B2; }

    __shared__ __attribute__((aligned(16))) u16 sA[MI * 32 * 32];
    __shared__ __attribute__((aligned(16))) u16 sB[128 * 32];

    const int t = threadIdx.x;
    const int w = t >> 6, L = t & 63;
    const int wm = w >> 1, wn = w & 1;
    const int lr = L & 15, lq = L >> 4;
    const int wbase = t & 192;                   // wave*64
    const int m0 = blockIdx.y * (MI * 32), n0 = blockIdx.x * 128;

    f32x4 acc[MI][4];
#pragma unroll
    for (int i = 0; i < MI; i++)
#pragma unroll
        for (int j = 0; j < 4; j++) { f32x4 z = {0.f, 0.f, 0.f, 0.f}; acc[i][j] = z; }

    for (int k0 = 0; k0 < EMB; k0 += 32) {
        __syncthreads();
        // stage A: MI*128 chunks of 8 elems; swizzle col8 = cc ^ (row&3)
#pragma unroll
        for (int q = 0; q < MI / 2; q++) {
            int c = q * 256 + t;
            int row = c >> 2, cc = c & 3;
            int col8 = cc ^ (row & 3);
            GLOAD_LDS16(&A[(size_t)(m0 + row) * EMB + k0 + col8 * 8],
                        &sA[(q * 256 + wbase) * 8]);
        }
        // stage B: 512 chunks
#pragma unroll
        for (int q = 0; q < 2; q++) {
            int c = q * 256 + t;
            int row = c >> 2, cc = c & 3;
            int col8 = cc ^ (row & 3);
            GLOAD_LDS16(&W[(size_t)(n0 + row) * EMB + k0 + col8 * 8],
                        &sB[(q * 256 + wbase) * 8]);
        }
        __syncthreads();
        bf16x8 af[MI], bfr[4];
#pragma unroll
        for (int mi = 0; mi < MI; mi++) {
            int row = wm * (MI * 16) + mi * 16 + lr;
            af[mi] = ldfrag(&sA[(row * 4 + (lq ^ (row & 3))) * 8]);
        }
#pragma unroll
        for (int ni = 0; ni < 4; ni++) {
            int row = wn * 64 + ni * 16 + lr;
            bfr[ni] = ldfrag(&sB[(row * 4 + (lq ^ (row & 3))) * 8]);
        }
#pragma unroll
        for (int mi = 0; mi < MI; mi++)
#pragma unroll
            for (int ni = 0; ni < 4; ni++)
                acc[mi][ni] = MFMA16(af[mi], bfr[ni], acc[mi][ni]);
    }

    const float lamf = lam[0];
#pragma unroll
    for (int mi = 0; mi < MI; mi++)
#pragma unroll
        for (int ni = 0; ni < 4; ni++) {
            int mb = m0 + wm * (MI * 16) + mi * 16 + lq * 4;
            int n  = n0 + wn * 64 + ni * 16 + lr;
            float bv = bias[n];
            if (mode == 3) {
#pragma unroll
                for (int r = 0; r < 4; r++)
                    out[(size_t)(mb + r) * EMB + n] = acc[mi][ni][r] + bv;
            } else {
                int b = mb >> 11, s0 = mb & 2047;
                int h = n >> 6,  d = n & 63;
                if (mode == 0) {
#pragma unroll
                    for (int r = 0; r < 4; r++) {
                        float val = acc[mi][ni][r] + bv;
                        size_t i128 = ((size_t)(b * NH + h) * SEQ + s0 + r) * 128 + d;
                        Qa[i128]      = f2b(val * 0.125f);
                        Qa[i128 + 64] = f2b(lamf * tanhf(val));
                    }
                } else if (mode == 1) {
#pragma unroll
                    for (int r = 0; r < 4; r++) {
                        float val = acc[mi][ni][r] + bv;
                        Ka[((size_t)(b * NH + h) * SEQ + s0 + r) * 128 + d] = f2b(val);
                    }
                } else {
                    u16x4 pk;
#pragma unroll
                    for (int r = 0; r < 4; r++) pk[r] = f2b(acc[mi][ni][r] + bv);
                    *(u16x4*)&Vt[((size_t)(b * NH + h) * HD + d) * SEQ + s0] = pk;
                }
            }
        }
}

// ---------------------------------------------------------------------------
// U kernel: Ka[:,64:128] = tanh(K) @ J_h^T per (b,h); K read from Ka[:,0:64]
// grid: (S/64, B*H), 256 threads
// ---------------------------------------------------------------------------
__global__ __launch_bounds__(256) void ukern(
        const float* __restrict__ J, u16* __restrict__ Ka)
{
    __shared__ __attribute__((aligned(16))) u16 sJ[64 * 72];
    const int t = threadIdx.x, w = t >> 6, L = t & 63, lr = L & 15, lq = L >> 4;
    const int rt = blockIdx.x, bh = blockIdx.y, h = bh & 15;

#pragma unroll
    for (int i = 0; i < 2; i++) {
        int c = t + 256 * i;
        int row = c >> 3, col = (c & 7) * 8;
        *(bf16x8*)&sJ[row * 72 + col] = cvt8(&J[(size_t)h * 4096 + row * 64 + col]);
    }
    __syncthreads();

    const u16* krow = &Ka[((size_t)bh * SEQ + rt * 64 + w * 16 + lr) * 128];
    bf16x8 a0 = tanh8(ldfrag(krow + lq * 8));
    bf16x8 a1 = tanh8(ldfrag(krow + lq * 8 + 32));
#pragma unroll
    for (int nt = 0; nt < 4; nt++) {
        f32x4 acc = {0.f, 0.f, 0.f, 0.f};
        acc = MFMA16(a0, ldfrag(&sJ[(nt * 16 + lr) * 72 + lq * 8]), acc);
        acc = MFMA16(a1, ldfrag(&sJ[(nt * 16 + lr) * 72 + lq * 8 + 32]), acc);
#pragma unroll
        for (int r = 0; r < 4; r++) {
            int j = rt * 64 + w * 16 + lq * 4 + r;
            Ka[((size_t)bh * SEQ + j) * 128 + 64 + nt * 16 + lr] = f2b(acc[r]);
        }
    }
}

// ---------------------------------------------------------------------------
// Causal flash, S^T formulation: S^T = Ka_tile @ Qa_wave^T, per-lane softmax
// stats (one q-row per lane), P wave-private in LDS, O^T = V^T @ P^T.
// grid: (32 q-tiles [longest first], B*H), 256 thr. BM=BN=64, Dqk=128, Dv=64.
// ---------------------------------------------------------------------------
__global__ __launch_bounds__(256) void flash(
        const u16* __restrict__ Qa, const u16* __restrict__ Ka,
        const u16* __restrict__ Vt, u16* __restrict__ attn)
{
    __shared__ __attribute__((aligned(16))) u16 sK[64 * 128];   // swizzled chunks
    __shared__ __attribute__((aligned(16))) u16 sVt[64 * 64];   // swizzled chunks
    __shared__ __attribute__((aligned(16))) u16 sP[64 * 72];    // padded rows

    const int t = threadIdx.x, w = t >> 6, L = t & 63, lr = L & 15, lq = L >> 4;
    const int qt = (int)gridDim.x - 1 - (int)blockIdx.x;   // longest first
    const int bh = blockIdx.y;
    const int qm = qt * 64;
    const int i_l = w * 16 + lr;            // this lane's q-row (block-local)
    const int wbase = t & 192;

    // Q fragments as B-operand: B[n=i][k], k-chunk = s*32 + lq*8
    bf16x8 qf[4];
    {
        const u16* qrow = Qa + ((size_t)bh * SEQ + qm + i_l) * 128;
#pragma unroll
        for (int s = 0; s < 4; s++) qf[s] = ldfrag(qrow + s * 32 + lq * 8);
    }

    f32x4 Ot[4];                            // O^T: rows d (4 mt-tiles), col i
#pragma unroll
    for (int i = 0; i < 4; i++) { f32x4 z = {0.f, 0.f, 0.f, 0.f}; Ot[i] = z; }
    float mrun = -INFINITY, lrun = 0.f;

    for (int kt = 0; kt <= qt; kt++) {
        const int kn = kt * 64;
        __syncthreads();
        // stage K tile 64x128: 1024 chunks, swizzle col8 = cc ^ (row&15)
#pragma unroll
        for (int q = 0; q < 4; q++) {
            int c = q * 256 + t;
            int row = c >> 4, cc = c & 15;
            int col8 = cc ^ (row & 15);
            GLOAD_LDS16(&Ka[((size_t)bh * SEQ + kn + row) * 128 + col8 * 8],
                        &sK[(q * 256 + wbase) * 8]);
        }
        // stage V^T tile 64x64: 512 chunks, swizzle j8 = cc ^ (d&7)
#pragma unroll
        for (int q = 0; q < 2; q++) {
            int c = q * 256 + t;
            int d = c >> 3, cc = c & 7;
            int j8 = cc ^ (d & 7);
            GLOAD_LDS16(&Vt[((size_t)bh * HD + d) * SEQ + kn + j8 * 8],
                        &sVt[(q * 256 + wbase) * 8]);
        }
        __syncthreads();

        // S^T[j][i]: A = K rows j from LDS, B = Q (regs)
        f32x4 sc[4];
#pragma unroll
        for (int mt = 0; mt < 4; mt++) {
            int j = mt * 16 + lr;
            f32x4 a = {0.f, 0.f, 0.f, 0.f};
#pragma unroll
            for (int s = 0; s < 4; s++) {
                int q = s * 4 + lq;
                a = MFMA16(ldfrag(&sK[(j * 16 + (q ^ (j & 15))) * 8]), qf[s], a);
            }
            sc[mt] = a;
        }
        if (kt == qt) {
#pragma unroll
            for (int mt = 0; mt < 4; mt++)
#pragma unroll
                for (int r = 0; r < 4; r++)
                    if (mt * 16 + lq * 4 + r > i_l) sc[mt][r] = -INFINITY;
        }
        // per-lane online softmax (lane owns one q-row; j spread over lq)
        float mx = -INFINITY;
#pragma unroll
        for (int mt = 0; mt < 4; mt++)
#pragma unroll
            for (int r = 0; r < 4; r++) mx = fmaxf(mx, sc[mt][r]);
        mx = fmaxf(mx, __shfl_xor(mx, 16));
        mx = fmaxf(mx, __shfl_xor(mx, 32));
        float mnew = fmaxf(mrun, mx);
        float alpha = (mrun == -INFINITY) ? 0.f : __expf(mrun - mnew);
        float sum = 0.f;
#pragma unroll
        for (int mt = 0; mt < 4; mt++)
#pragma unroll
            for (int r = 0; r < 4; r++) {
                sc[mt][r] = __expf(sc[mt][r] - mnew);
                sum += sc[mt][r];
            }
        sum += __shfl_xor(sum, 16);
        sum += __shfl_xor(sum, 32);
        lrun = lrun * alpha + sum;
        mrun = mnew;
#pragma unroll
        for (int mt = 0; mt < 4; mt++) Ot[mt] *= alpha;
        // P^T -> sP row-major [i][j]; wave-private rows, packed b64 writes
#pragma unroll
        for (int mt = 0; mt < 4; mt++) {
            u16x4 pk;
#pragma unroll
            for (int r = 0; r < 4; r++) pk[r] = f2b(sc[mt][r]);
            *(u16x4*)&sP[i_l * 72 + mt * 16 + lq * 4] = pk;
        }
        // O^T[d][i] += V^T[d][j] * P[i][j]: A = sVt, B = sP (contiguous b128)
#pragma unroll
        for (int s2 = 0; s2 < 2; s2++) {
            bf16x8 pf = ldfrag(&sP[i_l * 72 + s2 * 32 + lq * 8]);
#pragma unroll
            for (int mt = 0; mt < 4; mt++) {
                int d = mt * 16 + lr;
                int q = s2 * 4 + lq;
                Ot[mt] = MFMA16(ldfrag(&sVt[(d * 8 + (q ^ (d & 7))) * 8]), pf, Ot[mt]);
            }
        }
    }

    // epilogue: lane col i = i_l, rows d = mt*16 + lq*4 + r
    const float inv = 1.0f / lrun;
    const int b = bh >> 4, h = bh & 15;
    const size_t base = ((size_t)(b * SEQ + qm + i_l)) * EMB + h * HD;
#pragma unroll
    for (int mt = 0; mt < 4; mt++) {
        u16x4 pk;
#pragma unroll
        for (int r = 0; r < 4; r++) pk[r] = f2b(Ot[mt][r] * inv);
        *(u16x4*)&attn[base + mt * 16 + lq * 4] = pk;
    }
}

// ---------------------------------------------------------------------------
extern "C" void kernel_launch(void* const* d_in, const int* in_sizes, int n_in,
                              void* d_out, int out_size, void* d_ws, size_t ws_size,
                              hipStream_t stream)
{
    const float* x   = (const float*)d_in[0];
    const float* Wq  = (const float*)d_in[1];
    const float* bq  = (const float*)d_in[2];
    const float* Wk  = (const float*)d_in[3];
    const float* bk  = (const float*)d_in[4];
    const float* Wv  = (const float*)d_in[5];
    const float* bv  = (const float*)d_in[6];
    const float* Wo  = (const float*)d_in[7];
    const float* bo  = (const float*)d_in[8];
    const float* J   = (const float*)d_in[9];
    const float* lam = (const float*)d_in[10];

    u16* ws  = (u16*)d_ws;
    u16* xb  = ws;                                   // 4096*1024 bf16 (reused as attn)
    u16* Wqb = xb  + (size_t)4096 * 1024;
    u16* Wkb = Wqb + (size_t)1024 * 1024;
    u16* Wvb = Wkb + (size_t)1024 * 1024;
    u16* Wob = Wvb + (size_t)1024 * 1024;
    u16* Qa  = Wob + (size_t)1024 * 1024;            // 32*2048*128
    u16* Ka  = Qa  + (size_t)32 * 2048 * 128;        // 32*2048*128
    u16* Vt  = Ka  + (size_t)32 * 2048 * 128;        // 32*64*2048 (b,h,d,s)
    u16* attn = xb;                                  // alias: xb dead after QKV
    float* dout = (float*)d_out;

    dim3 blk(256);
    // fp32 -> bf16 for x and the four weight matrices
    cvt_all<<<dim3(4096), blk, 0, stream>>>(x, Wq, Wk, Wv, Wo, ws);
    // fused Q/K/V projections
    gemm_epi<4><<<dim3(8, 32, 3), blk, 0, stream>>>(
        xb, Wqb, bq, Wkb, bk, Wvb, bv, lam, Qa, Ka, Vt, dout, 0);
    // Ka[:,64:128] = tanh(K) @ J_h^T
    ukern<<<dim3(32, 32), blk, 0, stream>>>(J, Ka);
    // causal flash attention, augmented 128-dim QK
    flash<<<dim3(32, 32), blk, 0, stream>>>(Qa, Ka, Vt, attn);
    // output projection (64-row tiles -> 512 blocks for occupancy)
    gemm_epi<2><<<dim3(8, 64, 1), blk, 0, stream>>>(
        attn, Wob, bo, Wob, bo, Wob, bo, lam, Qa, Ka, Vt, dout, 3);
}

// Round 4
// 237.041 us; speedup vs baseline: 1.6111x; 1.1594x over previous
//
#include <hip/hip_runtime.h>
#include <hip/hip_bf16.h>

typedef unsigned short u16;
typedef __bf16 bf16x8 __attribute__((ext_vector_type(8)));
typedef float f32x4 __attribute__((ext_vector_type(4)));
typedef unsigned short u16x4 __attribute__((ext_vector_type(4)));

#define MFMA16(a, b, c) __builtin_amdgcn_mfma_f32_16x16x32_bf16(a, b, c, 0, 0, 0)

#define EMB 1024
#define SEQ 2048
#define NH 16
#define HD 64
#define LOG2E 1.4426950408889634f

// async global->LDS, 16B per lane; LDS dest = wave-uniform base + lane*16
#define GLOAD_LDS16(g, l) __builtin_amdgcn_global_load_lds( \
    (const __attribute__((address_space(1))) unsigned int*)(g), \
    (__attribute__((address_space(3))) unsigned int*)(l), 16, 0, 0)

__device__ __forceinline__ float b2f(u16 u) {
    union { unsigned int i; float f; } v; v.i = ((unsigned int)u) << 16; return v.f;
}
__device__ __forceinline__ u16 f2b(float f) {
    __hip_bfloat16 h = __float2bfloat16(f);
    return *reinterpret_cast<u16*>(&h);
}
__device__ __forceinline__ bf16x8 ldfrag(const u16* p) {
    return *reinterpret_cast<const bf16x8*>(p);
}
__device__ __forceinline__ bf16x8 cvt8(const float* p) {
    const float4 a = *reinterpret_cast<const float4*>(p);
    const float4 b = *reinterpret_cast<const float4*>(p + 4);
    union { bf16x8 v; u16 u[8]; } r;
    r.u[0] = f2b(a.x); r.u[1] = f2b(a.y); r.u[2] = f2b(a.z); r.u[3] = f2b(a.w);
    r.u[4] = f2b(b.x); r.u[5] = f2b(b.y); r.u[6] = f2b(b.z); r.u[7] = f2b(b.w);
    return r.v;
}
__device__ __forceinline__ bf16x8 tanh8(bf16x8 v) {
    union { bf16x8 v; u16 u[8]; } in, out; in.v = v;
#pragma unroll
    for (int e = 0; e < 8; e++) out.u[e] = f2b(tanhf(b2f(in.u[e])));
    return out.v;
}

// ---------------------------------------------------------------------------
// fp32 -> bf16 conversion: [x (4096x1024) | Wq | Wk | Wv | Wo] -> ws bf16
// ---------------------------------------------------------------------------
__global__ __launch_bounds__(256) void cvt_all(
        const float* __restrict__ x,  const float* __restrict__ Wq,
        const float* __restrict__ Wk, const float* __restrict__ Wv,
        const float* __restrict__ Wo, u16* __restrict__ dst)
{
    size_t i = ((size_t)blockIdx.x * 256 + threadIdx.x) * 8;
    const float* src; size_t off;
    if (i < 4194304) { src = x; off = i; }
    else {
        size_t j = i - 4194304; int w = (int)(j >> 20); off = j & 1048575;
        src = (w == 0) ? Wq : (w == 1) ? Wk : (w == 2) ? Wv : Wo;
    }
    *(bf16x8*)&dst[i] = cvt8(src + off);
}

// ---------------------------------------------------------------------------
// GEMM: C = A(MxK,bf16) @ W(NxK,bf16)^T + bias(fp32). Tile MI*32 x 128, BK=32.
// 256 thr = 4 waves (2x2). Staging via global_load_lds + XOR chunk swizzle.
// mode 0: Qa[:,0:64]=Q/8*log2e, Qa[:,64:128]=lam*log2e*tanh(Q) (B,H,S,128)
// mode 1: Ka[:,0:64]=K                                (B,H,S,128) bf16
// mode 2: Vt[b,h,d,s]=V  (transposed)                 (B,H,HD,S)  bf16
// mode 3: out = val fp32 (row-major M x EMB)
// ---------------------------------------------------------------------------
template<int MI>   // m-frags per wave (4 -> 128-row tile, 2 -> 64-row tile)
__global__ __launch_bounds__(256) void gemm_epi(
        const u16* __restrict__ A,
        const u16* __restrict__ W0, const float* __restrict__ B0,
        const u16* __restrict__ W1, const float* __restrict__ B1,
        const u16* __restrict__ W2, const float* __restrict__ B2,
        const float* __restrict__ lam,
        u16* __restrict__ Qa, u16* __restrict__ Ka, u16* __restrict__ Vt,
        float* __restrict__ out, int modeBase)
{
    const int mode = modeBase + blockIdx.z;
    const u16* W; const float* bias;
    if (blockIdx.z == 0)      { W = W0; bias = B0; }
    else if (blockIdx.z == 1) { W = W1; bias = B1; }
    else                      { W = W2; bias = B2; }

    __shared__ __attribute__((aligned(16))) u16 sA[MI * 32 * 32];
    __shared__ __attribute__((aligned(16))) u16 sB[128 * 32];

    const int t = threadIdx.x;
    const int w = t >> 6, L = t & 63;
    const int wm = w >> 1, wn = w & 1;
    const int lr = L & 15, lq = L >> 4;
    const int wbase = t & 192;                   // wave*64
    const int m0 = blockIdx.y * (MI * 32), n0 = blockIdx.x * 128;

    f32x4 acc[MI][4];
#pragma unroll
    for (int i = 0; i < MI; i++)
#pragma unroll
        for (int j = 0; j < 4; j++) { f32x4 z = {0.f, 0.f, 0.f, 0.f}; acc[i][j] = z; }

    for (int k0 = 0; k0 < EMB; k0 += 32) {
        __syncthreads();
        // stage A: MI*128 chunks of 8 elems; swizzle col8 = cc ^ (row&3)
#pragma unroll
        for (int q = 0; q < MI / 2; q++) {
            int c = q * 256 + t;
            int row = c >> 2, cc = c & 3;
            int col8 = cc ^ (row & 3);
            GLOAD_LDS16(&A[(size_t)(m0 + row) * EMB + k0 + col8 * 8],
                        &sA[(q * 256 + wbase) * 8]);
        }
        // stage B: 512 chunks
#pragma unroll
        for (int q = 0; q < 2; q++) {
            int c = q * 256 + t;
            int row = c >> 2, cc = c & 3;
            int col8 = cc ^ (row & 3);
            GLOAD_LDS16(&W[(size_t)(n0 + row) * EMB + k0 + col8 * 8],
                        &sB[(q * 256 + wbase) * 8]);
        }
        __syncthreads();
        bf16x8 af[MI], bfr[4];
#pragma unroll
        for (int mi = 0; mi < MI; mi++) {
            int row = wm * (MI * 16) + mi * 16 + lr;
            af[mi] = ldfrag(&sA[(row * 4 + (lq ^ (row & 3))) * 8]);
        }
#pragma unroll
        for (int ni = 0; ni < 4; ni++) {
            int row = wn * 64 + ni * 16 + lr;
            bfr[ni] = ldfrag(&sB[(row * 4 + (lq ^ (row & 3))) * 8]);
        }
#pragma unroll
        for (int mi = 0; mi < MI; mi++)
#pragma unroll
            for (int ni = 0; ni < 4; ni++)
                acc[mi][ni] = MFMA16(af[mi], bfr[ni], acc[mi][ni]);
    }

    const float lamf = lam[0];
#pragma unroll
    for (int mi = 0; mi < MI; mi++)
#pragma unroll
        for (int ni = 0; ni < 4; ni++) {
            int mb = m0 + wm * (MI * 16) + mi * 16 + lq * 4;
            int n  = n0 + wn * 64 + ni * 16 + lr;
            float bv = bias[n];
            if (mode == 3) {
#pragma unroll
                for (int r = 0; r < 4; r++)
                    out[(size_t)(mb + r) * EMB + n] = acc[mi][ni][r] + bv;
            } else {
                int b = mb >> 11, s0 = mb & 2047;
                int h = n >> 6,  d = n & 63;
                if (mode == 0) {
#pragma unroll
                    for (int r = 0; r < 4; r++) {
                        float val = acc[mi][ni][r] + bv;
                        size_t i128 = ((size_t)(b * NH + h) * SEQ + s0 + r) * 128 + d;
                        Qa[i128]      = f2b(val * (0.125f * LOG2E));
                        Qa[i128 + 64] = f2b(lamf * LOG2E * tanhf(val));
                    }
                } else if (mode == 1) {
#pragma unroll
                    for (int r = 0; r < 4; r++) {
                        float val = acc[mi][ni][r] + bv;
                        Ka[((size_t)(b * NH + h) * SEQ + s0 + r) * 128 + d] = f2b(val);
                    }
                } else {
                    u16x4 pk;
#pragma unroll
                    for (int r = 0; r < 4; r++) pk[r] = f2b(acc[mi][ni][r] + bv);
                    *(u16x4*)&Vt[((size_t)(b * NH + h) * HD + d) * SEQ + s0] = pk;
                }
            }
        }
}

// ---------------------------------------------------------------------------
// U kernel: Ka[:,64:128] = tanh(K) @ J_h^T per (b,h); K read from Ka[:,0:64]
// grid: (S/64, B*H), 256 threads
// ---------------------------------------------------------------------------
__global__ __launch_bounds__(256) void ukern(
        const float* __restrict__ J, u16* __restrict__ Ka)
{
    __shared__ __attribute__((aligned(16))) u16 sJ[64 * 72];
    const int t = threadIdx.x, w = t >> 6, L = t & 63, lr = L & 15, lq = L >> 4;
    const int rt = blockIdx.x, bh = blockIdx.y, h = bh & 15;

#pragma unroll
    for (int i = 0; i < 2; i++) {
        int c = t + 256 * i;
        int row = c >> 3, col = (c & 7) * 8;
        *(bf16x8*)&sJ[row * 72 + col] = cvt8(&J[(size_t)h * 4096 + row * 64 + col]);
    }
    __syncthreads();

    const u16* krow = &Ka[((size_t)bh * SEQ + rt * 64 + w * 16 + lr) * 128];
    bf16x8 a0 = tanh8(ldfrag(krow + lq * 8));
    bf16x8 a1 = tanh8(ldfrag(krow + lq * 8 + 32));
#pragma unroll
    for (int nt = 0; nt < 4; nt++) {
        f32x4 acc = {0.f, 0.f, 0.f, 0.f};
        acc = MFMA16(a0, ldfrag(&sJ[(nt * 16 + lr) * 72 + lq * 8]), acc);
        acc = MFMA16(a1, ldfrag(&sJ[(nt * 16 + lr) * 72 + lq * 8 + 32]), acc);
#pragma unroll
        for (int r = 0; r < 4; r++) {
            int j = rt * 64 + w * 16 + lq * 4 + r;
            Ka[((size_t)bh * SEQ + j) * 128 + 64 + nt * 16 + lr] = f2b(acc[r]);
        }
    }
}

// ---------------------------------------------------------------------------
// Causal flash, S^T formulation: S^T = Ka_tile @ Qa_wave^T, per-lane softmax
// stats (one q-row per lane), P wave-private in LDS, O^T = V^T @ P^T.
// grid: (256, 4). Block mapping: c=bx: bh=c&31, p=c>>5; s=by:
//   qt = {p, 15-p, 16+p, 31-p}[s]
// -> per-CU iter sum = 66 for every round-robin quartet {c, c+256, ...}
// -> all blocks of one bh land on CUs ≡ bh (mod 8) => same XCD, K/V L2-resident
// ---------------------------------------------------------------------------
__global__ __launch_bounds__(256) void flash(
        const u16* __restrict__ Qa, const u16* __restrict__ Ka,
        const u16* __restrict__ Vt, u16* __restrict__ attn)
{
    __shared__ __attribute__((aligned(16))) u16 sK[64 * 128];   // swizzled chunks
    __shared__ __attribute__((aligned(16))) u16 sVt[64 * 64];   // swizzled chunks
    __shared__ __attribute__((aligned(16))) u16 sP[64 * 72];    // padded rows

    const int t = threadIdx.x, w = t >> 6, L = t & 63, lr = L & 15, lq = L >> 4;
    const int c = blockIdx.x, s_ = blockIdx.y;
    const int bh = c & 31, p = c >> 5;
    const int qt = (s_ == 0) ? p : (s_ == 1) ? 15 - p : (s_ == 2) ? 16 + p : 31 - p;
    const int qm = qt * 64;
    const int i_l = w * 16 + lr;            // this lane's q-row (block-local)
    const int wbase = t & 192;

    // Q fragments as B-operand: B[n=i][k], k-chunk = s*32 + lq*8
    bf16x8 qf[4];
    {
        const u16* qrow = Qa + ((size_t)bh * SEQ + qm + i_l) * 128;
#pragma unroll
        for (int s = 0; s < 4; s++) qf[s] = ldfrag(qrow + s * 32 + lq * 8);
    }

    f32x4 Ot[4];                            // O^T: rows d (4 mt-tiles), col i
#pragma unroll
    for (int i = 0; i < 4; i++) { f32x4 z = {0.f, 0.f, 0.f, 0.f}; Ot[i] = z; }
    float mrun = -INFINITY, lrun = 0.f;

    for (int kt = 0; kt <= qt; kt++) {
        const int kn = kt * 64;
        __syncthreads();
        // stage K tile 64x128: 1024 chunks, swizzle col8 = cc ^ (row&15)
#pragma unroll
        for (int q = 0; q < 4; q++) {
            int cch = q * 256 + t;
            int row = cch >> 4, cc = cch & 15;
            int col8 = cc ^ (row & 15);
            GLOAD_LDS16(&Ka[((size_t)bh * SEQ + kn + row) * 128 + col8 * 8],
                        &sK[(q * 256 + wbase) * 8]);
        }
        // stage V^T tile 64x64: 512 chunks, swizzle j8 = cc ^ (d&7)
#pragma unroll
        for (int q = 0; q < 2; q++) {
            int cch = q * 256 + t;
            int d = cch >> 3, cc = cch & 7;
            int j8 = cc ^ (d & 7);
            GLOAD_LDS16(&Vt[((size_t)bh * HD + d) * SEQ + kn + j8 * 8],
                        &sVt[(q * 256 + wbase) * 8]);
        }
        __syncthreads();

        // S^T[j][i]: A = K rows j from LDS, B = Q (regs); units: score*log2e
        f32x4 sc[4];
#pragma unroll
        for (int mt = 0; mt < 4; mt++) {
            int j = mt * 16 + lr;
            f32x4 a = {0.f, 0.f, 0.f, 0.f};
#pragma unroll
            for (int s = 0; s < 4; s++) {
                int q = s * 4 + lq;
                a = MFMA16(ldfrag(&sK[(j * 16 + (q ^ (j & 15))) * 8]), qf[s], a);
            }
            sc[mt] = a;
        }
        if (kt == qt) {
#pragma unroll
            for (int mt = 0; mt < 4; mt++)
#pragma unroll
                for (int r = 0; r < 4; r++)
                    if (mt * 16 + lq * 4 + r > i_l) sc[mt][r] = -INFINITY;
        }
        // per-lane online softmax (lane owns one q-row; j spread over lq)
        float mx = -INFINITY;
#pragma unroll
        for (int mt = 0; mt < 4; mt++)
#pragma unroll
            for (int r = 0; r < 4; r++) mx = fmaxf(mx, sc[mt][r]);
        mx = fmaxf(mx, __shfl_xor(mx, 16));
        mx = fmaxf(mx, __shfl_xor(mx, 32));
        float mnew = fmaxf(mrun, mx);
        float alpha = exp2f(mrun - mnew);   // mnew finite always; exp2(-inf)=0
        float sum = 0.f;
#pragma unroll
        for (int mt = 0; mt < 4; mt++)
#pragma unroll
            for (int r = 0; r < 4; r++) {
                sc[mt][r] = exp2f(sc[mt][r] - mnew);
                sum += sc[mt][r];
            }
        sum += __shfl_xor(sum, 16);
        sum += __shfl_xor(sum, 32);
        lrun = lrun * alpha + sum;
        mrun = mnew;
#pragma unroll
        for (int mt = 0; mt < 4; mt++) Ot[mt] *= alpha;
        // P^T -> sP row-major [i][j]; wave-private rows, packed b64 writes
#pragma unroll
        for (int mt = 0; mt < 4; mt++) {
            u16x4 pk;
#pragma unroll
            for (int r = 0; r < 4; r++) pk[r] = f2b(sc[mt][r]);
            *(u16x4*)&sP[i_l * 72 + mt * 16 + lq * 4] = pk;
        }
        // O^T[d][i] += V^T[d][j] * P[i][j]: A = sVt, B = sP (contiguous b128)
#pragma unroll
        for (int s2 = 0; s2 < 2; s2++) {
            bf16x8 pf = ldfrag(&sP[i_l * 72 + s2 * 32 + lq * 8]);
#pragma unroll
            for (int mt = 0; mt < 4; mt++) {
                int d = mt * 16 + lr;
                int q = s2 * 4 + lq;
                Ot[mt] = MFMA16(ldfrag(&sVt[(d * 8 + (q ^ (d & 7))) * 8]), pf, Ot[mt]);
            }
        }
    }

    // epilogue: lane col i = i_l, rows d = mt*16 + lq*4 + r
    const float inv = 1.0f / lrun;
    const int b = bh >> 4, h = bh & 15;
    const size_t base = ((size_t)(b * SEQ + qm + i_l)) * EMB + h * HD;
#pragma unroll
    for (int mt = 0; mt < 4; mt++) {
        u16x4 pk;
#pragma unroll
        for (int r = 0; r < 4; r++) pk[r] = f2b(Ot[mt][r] * inv);
        *(u16x4*)&attn[base + mt * 16 + lq * 4] = pk;
    }
}

// ---------------------------------------------------------------------------
extern "C" void kernel_launch(void* const* d_in, const int* in_sizes, int n_in,
                              void* d_out, int out_size, void* d_ws, size_t ws_size,
                              hipStream_t stream)
{
    const float* x   = (const float*)d_in[0];
    const float* Wq  = (const float*)d_in[1];
    const float* bq  = (const float*)d_in[2];
    const float* Wk  = (const float*)d_in[3];
    const float* bk  = (const float*)d_in[4];
    const float* Wv  = (const float*)d_in[5];
    const float* bv  = (const float*)d_in[6];
    const float* Wo  = (const float*)d_in[7];
    const float* bo  = (const float*)d_in[8];
    const float* J   = (const float*)d_in[9];
    const float* lam = (const float*)d_in[10];

    u16* ws  = (u16*)d_ws;
    u16* xb  = ws;                                   // 4096*1024 bf16 (reused as attn)
    u16* Wqb = xb  + (size_t)4096 * 1024;
    u16* Wkb = Wqb + (size_t)1024 * 1024;
    u16* Wvb = Wkb + (size_t)1024 * 1024;
    u16* Wob = Wvb + (size_t)1024 * 1024;
    u16* Qa  = Wob + (size_t)1024 * 1024;            // 32*2048*128
    u16* Ka  = Qa  + (size_t)32 * 2048 * 128;        // 32*2048*128
    u16* Vt  = Ka  + (size_t)32 * 2048 * 128;        // 32*64*2048 (b,h,d,s)
    u16* attn = xb;                                  // alias: xb dead after QKV
    float* dout = (float*)d_out;

    dim3 blk(256);
    // fp32 -> bf16 for x and the four weight matrices
    cvt_all<<<dim3(4096), blk, 0, stream>>>(x, Wq, Wk, Wv, Wo, ws);
    // fused Q/K/V projections
    gemm_epi<4><<<dim3(8, 32, 3), blk, 0, stream>>>(
        xb, Wqb, bq, Wkb, bk, Wvb, bv, lam, Qa, Ka, Vt, dout, 0);
    // Ka[:,64:128] = tanh(K) @ J_h^T
    ukern<<<dim3(32, 32), blk, 0, stream>>>(J, Ka);
    // causal flash attention, augmented 128-dim QK (balanced + XCD-local map)
    flash<<<dim3(256, 4), blk, 0, stream>>>(Qa, Ka, Vt, attn);
    // output projection (64-row tiles -> 512 blocks for occupancy)
    gemm_epi<2><<<dim3(8, 64, 1), blk, 0, stream>>>(
        attn, Wob, bo, Wob, bo, Wob, bo, lam, Qa, Ka, Vt, dout, 3);
}

// Round 5
// 215.046 us; speedup vs baseline: 1.7759x; 1.1023x over previous
//
#include <hip/hip_runtime.h>
#include <hip/hip_bf16.h>

typedef unsigned short u16;
typedef __bf16 bf16x8 __attribute__((ext_vector_type(8)));
typedef float f32x4 __attribute__((ext_vector_type(4)));
typedef unsigned short u16x4 __attribute__((ext_vector_type(4)));

#define MFMA16(a, b, c) __builtin_amdgcn_mfma_f32_16x16x32_bf16(a, b, c, 0, 0, 0)

#define EMB 1024
#define SEQ 2048
#define NH 16
#define HD 64
#define LOG2E 1.4426950408889634f

// async global->LDS, 16B per lane; LDS dest = wave-uniform base + lane*16
#define GLOAD_LDS16(g, l) __builtin_amdgcn_global_load_lds( \
    (const __attribute__((address_space(1))) unsigned int*)(g), \
    (__attribute__((address_space(3))) unsigned int*)(l), 16, 0, 0)

__device__ __forceinline__ float b2f(u16 u) {
    union { unsigned int i; float f; } v; v.i = ((unsigned int)u) << 16; return v.f;
}
__device__ __forceinline__ u16 f2b(float f) {
    __hip_bfloat16 h = __float2bfloat16(f);
    return *reinterpret_cast<u16*>(&h);
}
__device__ __forceinline__ u16x4 pack4(float a, float b, float c, float d) {
    union { __hip_bfloat162 h2[2]; u16x4 u; } r;
    r.h2[0] = __float22bfloat162_rn(float2{a, b});
    r.h2[1] = __float22bfloat162_rn(float2{c, d});
    return r.u;
}
__device__ __forceinline__ bf16x8 ldfrag(const u16* p) {
    return *reinterpret_cast<const bf16x8*>(p);
}
__device__ __forceinline__ bf16x8 cvt8(const float* p) {
    const float4 a = *reinterpret_cast<const float4*>(p);
    const float4 b = *reinterpret_cast<const float4*>(p + 4);
    union { u16x4 q[2]; bf16x8 v; } r;
    r.q[0] = pack4(a.x, a.y, a.z, a.w);
    r.q[1] = pack4(b.x, b.y, b.z, b.w);
    return r.v;
}
// tanh via hw exp2 + rcp: rel err < 1e-6, safe for |x| < 40
__device__ __forceinline__ float fast_tanh(float x) {
    float t = exp2f(x * (2.0f * LOG2E));
    return 1.0f - 2.0f * __builtin_amdgcn_rcpf(t + 1.0f);
}
__device__ __forceinline__ bf16x8 tanh8(bf16x8 v) {
    union { bf16x8 v; u16 u[8]; } in; in.v = v;
    float o[8];
#pragma unroll
    for (int e = 0; e < 8; e++) o[e] = fast_tanh(b2f(in.u[e]));
    union { u16x4 q[2]; bf16x8 v; } r;
    r.q[0] = pack4(o[0], o[1], o[2], o[3]);
    r.q[1] = pack4(o[4], o[5], o[6], o[7]);
    return r.v;
}

// ---------------------------------------------------------------------------
// fp32 -> bf16 conversion: [x (4096x1024) | Wq | Wk | Wv | Wo] -> ws bf16
// ---------------------------------------------------------------------------
__global__ __launch_bounds__(256) void cvt_all(
        const float* __restrict__ x,  const float* __restrict__ Wq,
        const float* __restrict__ Wk, const float* __restrict__ Wv,
        const float* __restrict__ Wo, u16* __restrict__ dst)
{
    size_t i = ((size_t)blockIdx.x * 256 + threadIdx.x) * 8;
    const float* src; size_t off;
    if (i < 4194304) { src = x; off = i; }
    else {
        size_t j = i - 4194304; int w = (int)(j >> 20); off = j & 1048575;
        src = (w == 0) ? Wq : (w == 1) ? Wk : (w == 2) ? Wv : Wo;
    }
    *(bf16x8*)&dst[i] = cvt8(src + off);
}

// ---------------------------------------------------------------------------
// GEMM: C = A(MxK,bf16) @ W(NxK,bf16)^T + bias(fp32). Tile MI*32 x 128, BK=32.
// 256 thr = 4 waves (2x2). Staging via global_load_lds + XOR chunk swizzle.
// mode 0: Qa[:,0:64]=Q/8*log2e, Qa[:,64:128]=lam*log2e*tanh(Q) (B,H,S,128)
// mode 1: Ka[:,0:64]=K                                (B,H,S,128) bf16
// mode 2: Vt[b,h,d,s]=V  (transposed)                 (B,H,HD,S)  bf16
// mode 3: out = val fp32 (row-major M x EMB)
// ---------------------------------------------------------------------------
template<int MI>   // m-frags per wave (4 -> 128-row tile, 2 -> 64-row tile)
__global__ __launch_bounds__(256) void gemm_epi(
        const u16* __restrict__ A,
        const u16* __restrict__ W0, const float* __restrict__ B0,
        const u16* __restrict__ W1, const float* __restrict__ B1,
        const u16* __restrict__ W2, const float* __restrict__ B2,
        const float* __restrict__ lam,
        u16* __restrict__ Qa, u16* __restrict__ Ka, u16* __restrict__ Vt,
        float* __restrict__ out, int modeBase)
{
    const int mode = modeBase + blockIdx.z;
    const u16* W; const float* bias;
    if (blockIdx.z == 0)      { W = W0; bias = B0; }
    else if (blockIdx.z == 1) { W = W1; bias = B1; }
    else                      { W = W2; bias = B2; }

    __shared__ __attribute__((aligned(16))) u16 sA[MI * 32 * 32];
    __shared__ __attribute__((aligned(16))) u16 sB[128 * 32];

    const int t = threadIdx.x;
    const int w = t >> 6, L = t & 63;
    const int wm = w >> 1, wn = w & 1;
    const int lr = L & 15, lq = L >> 4;
    const int wbase = t & 192;                   // wave*64
    const int m0 = blockIdx.y * (MI * 32), n0 = blockIdx.x * 128;

    f32x4 acc[MI][4];
#pragma unroll
    for (int i = 0; i < MI; i++)
#pragma unroll
        for (int j = 0; j < 4; j++) { f32x4 z = {0.f, 0.f, 0.f, 0.f}; acc[i][j] = z; }

    for (int k0 = 0; k0 < EMB; k0 += 32) {
        __syncthreads();
        // stage A: MI*128 chunks of 8 elems; swizzle col8 = cc ^ (row&3)
#pragma unroll
        for (int q = 0; q < MI / 2; q++) {
            int c = q * 256 + t;
            int row = c >> 2, cc = c & 3;
            int col8 = cc ^ (row & 3);
            GLOAD_LDS16(&A[(size_t)(m0 + row) * EMB + k0 + col8 * 8],
                        &sA[(q * 256 + wbase) * 8]);
        }
        // stage B: 512 chunks
#pragma unroll
        for (int q = 0; q < 2; q++) {
            int c = q * 256 + t;
            int row = c >> 2, cc = c & 3;
            int col8 = cc ^ (row & 3);
            GLOAD_LDS16(&W[(size_t)(n0 + row) * EMB + k0 + col8 * 8],
                        &sB[(q * 256 + wbase) * 8]);
        }
        __syncthreads();
        bf16x8 af[MI], bfr[4];
#pragma unroll
        for (int mi = 0; mi < MI; mi++) {
            int row = wm * (MI * 16) + mi * 16 + lr;
            af[mi] = ldfrag(&sA[(row * 4 + (lq ^ (row & 3))) * 8]);
        }
#pragma unroll
        for (int ni = 0; ni < 4; ni++) {
            int row = wn * 64 + ni * 16 + lr;
            bfr[ni] = ldfrag(&sB[(row * 4 + (lq ^ (row & 3))) * 8]);
        }
#pragma unroll
        for (int mi = 0; mi < MI; mi++)
#pragma unroll
            for (int ni = 0; ni < 4; ni++)
                acc[mi][ni] = MFMA16(af[mi], bfr[ni], acc[mi][ni]);
    }

    const float lamf = lam[0];
#pragma unroll
    for (int mi = 0; mi < MI; mi++)
#pragma unroll
        for (int ni = 0; ni < 4; ni++) {
            int mb = m0 + wm * (MI * 16) + mi * 16 + lq * 4;
            int n  = n0 + wn * 64 + ni * 16 + lr;
            float bv = bias[n];
            if (mode == 3) {
#pragma unroll
                for (int r = 0; r < 4; r++)
                    out[(size_t)(mb + r) * EMB + n] = acc[mi][ni][r] + bv;
            } else {
                int b = mb >> 11, s0 = mb & 2047;
                int h = n >> 6,  d = n & 63;
                if (mode == 0) {
#pragma unroll
                    for (int r = 0; r < 4; r++) {
                        float val = acc[mi][ni][r] + bv;
                        size_t i128 = ((size_t)(b * NH + h) * SEQ + s0 + r) * 128 + d;
                        Qa[i128]      = f2b(val * (0.125f * LOG2E));
                        Qa[i128 + 64] = f2b(lamf * LOG2E * fast_tanh(val));
                    }
                } else if (mode == 1) {
#pragma unroll
                    for (int r = 0; r < 4; r++) {
                        float val = acc[mi][ni][r] + bv;
                        Ka[((size_t)(b * NH + h) * SEQ + s0 + r) * 128 + d] = f2b(val);
                    }
                } else {
                    u16x4 pk = pack4(acc[mi][ni][0] + bv, acc[mi][ni][1] + bv,
                                     acc[mi][ni][2] + bv, acc[mi][ni][3] + bv);
                    *(u16x4*)&Vt[((size_t)(b * NH + h) * HD + d) * SEQ + s0] = pk;
                }
            }
        }
}

// ---------------------------------------------------------------------------
// U kernel: Ka[:,64:128] = tanh(K) @ J_h^T per (b,h); K read from Ka[:,0:64]
// grid: (S/64, B*H), 256 threads
// ---------------------------------------------------------------------------
__global__ __launch_bounds__(256) void ukern(
        const float* __restrict__ J, u16* __restrict__ Ka)
{
    __shared__ __attribute__((aligned(16))) u16 sJ[64 * 72];
    const int t = threadIdx.x, w = t >> 6, L = t & 63, lr = L & 15, lq = L >> 4;
    const int rt = blockIdx.x, bh = blockIdx.y, h = bh & 15;

#pragma unroll
    for (int i = 0; i < 2; i++) {
        int c = t + 256 * i;
        int row = c >> 3, col = (c & 7) * 8;
        *(bf16x8*)&sJ[row * 72 + col] = cvt8(&J[(size_t)h * 4096 + row * 64 + col]);
    }
    __syncthreads();

    const u16* krow = &Ka[((size_t)bh * SEQ + rt * 64 + w * 16 + lr) * 128];
    bf16x8 a0 = tanh8(ldfrag(krow + lq * 8));
    bf16x8 a1 = tanh8(ldfrag(krow + lq * 8 + 32));
#pragma unroll
    for (int nt = 0; nt < 4; nt++) {
        f32x4 acc = {0.f, 0.f, 0.f, 0.f};
        acc = MFMA16(a0, ldfrag(&sJ[(nt * 16 + lr) * 72 + lq * 8]), acc);
        acc = MFMA16(a1, ldfrag(&sJ[(nt * 16 + lr) * 72 + lq * 8 + 32]), acc);
#pragma unroll
        for (int r = 0; r < 4; r++) {
            int j = rt * 64 + w * 16 + lq * 4 + r;
            Ka[((size_t)bh * SEQ + j) * 128 + 64 + nt * 16 + lr] = f2b(acc[r]);
        }
    }
}

// ---------------------------------------------------------------------------
// Causal flash, S^T formulation. Scores are provably bounded (|s*log2e|<20),
// so softmax needs NO running max: P = exp2(s) raw, one sum-normalize at end.
// grid: (256, 4). Block mapping: c=bx: bh=c&31, p=c>>5; s=by:
//   qt = {p, 15-p, 16+p, 31-p}[s]
// -> per-CU iter sum = 66 for every round-robin quartet {c, c+256, ...}
// -> all blocks of one bh land on CUs ≡ bh (mod 8) => same XCD, K/V L2-resident
// ---------------------------------------------------------------------------
__global__ __launch_bounds__(256) void flash(
        const u16* __restrict__ Qa, const u16* __restrict__ Ka,
        const u16* __restrict__ Vt, u16* __restrict__ attn)
{
    __shared__ __attribute__((aligned(16))) u16 sK[64 * 128];   // swizzled chunks
    __shared__ __attribute__((aligned(16))) u16 sVt[64 * 64];   // swizzled chunks
    __shared__ __attribute__((aligned(16))) u16 sP[64 * 72];    // padded rows

    const int t = threadIdx.x, w = t >> 6, L = t & 63, lr = L & 15, lq = L >> 4;
    const int c = blockIdx.x, s_ = blockIdx.y;
    const int bh = c & 31, p = c >> 5;
    const int qt = (s_ == 0) ? p : (s_ == 1) ? 15 - p : (s_ == 2) ? 16 + p : 31 - p;
    const int qm = qt * 64;
    const int i_l = w * 16 + lr;            // this lane's q-row (block-local)
    const int wbase = t & 192;

    // Q fragments as B-operand: B[n=i][k], k-chunk = s*32 + lq*8
    bf16x8 qf[4];
    {
        const u16* qrow = Qa + ((size_t)bh * SEQ + qm + i_l) * 128;
#pragma unroll
        for (int s = 0; s < 4; s++) qf[s] = ldfrag(qrow + s * 32 + lq * 8);
    }

    f32x4 Ot[4];                            // O^T: rows d (4 mt-tiles), col i
#pragma unroll
    for (int i = 0; i < 4; i++) { f32x4 z = {0.f, 0.f, 0.f, 0.f}; Ot[i] = z; }
    float lsum = 0.f;                       // per-lane partial row-sum

    for (int kt = 0; kt <= qt; kt++) {
        const int kn = kt * 64;
        __syncthreads();
        // stage K tile 64x128: 1024 chunks, swizzle col8 = cc ^ (row&15)
#pragma unroll
        for (int q = 0; q < 4; q++) {
            int cch = q * 256 + t;
            int row = cch >> 4, cc = cch & 15;
            int col8 = cc ^ (row & 15);
            GLOAD_LDS16(&Ka[((size_t)bh * SEQ + kn + row) * 128 + col8 * 8],
                        &sK[(q * 256 + wbase) * 8]);
        }
        // stage V^T tile 64x64: 512 chunks, swizzle j8 = cc ^ (d&7)
#pragma unroll
        for (int q = 0; q < 2; q++) {
            int cch = q * 256 + t;
            int d = cch >> 3, cc = cch & 7;
            int j8 = cc ^ (d & 7);
            GLOAD_LDS16(&Vt[((size_t)bh * HD + d) * SEQ + kn + j8 * 8],
                        &sVt[(q * 256 + wbase) * 8]);
        }
        __syncthreads();

        // S^T[j][i]: A = K rows j from LDS, B = Q (regs); units: score*log2e
        f32x4 sc[4];
#pragma unroll
        for (int mt = 0; mt < 4; mt++) {
            int j = mt * 16 + lr;
            f32x4 a = {0.f, 0.f, 0.f, 0.f};
#pragma unroll
            for (int s = 0; s < 4; s++) {
                int q = s * 4 + lq;
                a = MFMA16(ldfrag(&sK[(j * 16 + (q ^ (j & 15))) * 8]), qf[s], a);
            }
            sc[mt] = a;
        }
        if (kt == qt) {
#pragma unroll
            for (int mt = 0; mt < 4; mt++)
#pragma unroll
                for (int r = 0; r < 4; r++)
                    if (mt * 16 + lq * 4 + r > i_l) sc[mt][r] = -INFINITY;
        }
        // no-max softmax: P = exp2(s) raw; per-lane sum accumulated
#pragma unroll
        for (int mt = 0; mt < 4; mt++)
#pragma unroll
            for (int r = 0; r < 4; r++) {
                float e = exp2f(sc[mt][r]);
                sc[mt][r] = e;
                lsum += e;
            }
        // P^T -> sP row-major [i][j]; wave-private rows, packed b64 writes
#pragma unroll
        for (int mt = 0; mt < 4; mt++)
            *(u16x4*)&sP[i_l * 72 + mt * 16 + lq * 4] =
                pack4(sc[mt][0], sc[mt][1], sc[mt][2], sc[mt][3]);
        // O^T[d][i] += V^T[d][j] * P[i][j]: A = sVt, B = sP (contiguous b128)
#pragma unroll
        for (int s2 = 0; s2 < 2; s2++) {
            bf16x8 pf = ldfrag(&sP[i_l * 72 + s2 * 32 + lq * 8]);
#pragma unroll
            for (int mt = 0; mt < 4; mt++) {
                int d = mt * 16 + lr;
                int q = s2 * 4 + lq;
                Ot[mt] = MFMA16(ldfrag(&sVt[(d * 8 + (q ^ (d & 7))) * 8]), pf, Ot[mt]);
            }
        }
    }

    // one cross-lane reduce at the end (row i spread over the 4 lq groups)
    lsum += __shfl_xor(lsum, 16);
    lsum += __shfl_xor(lsum, 32);
    const float inv = __builtin_amdgcn_rcpf(lsum) *
                      (2.0f - lsum * __builtin_amdgcn_rcpf(lsum)); // NR refine
    const int b = bh >> 4, h = bh & 15;
    const size_t base = ((size_t)(b * SEQ + qm + i_l)) * EMB + h * HD;
#pragma unroll
    for (int mt = 0; mt < 4; mt++)
        *(u16x4*)&attn[base + mt * 16 + lq * 4] =
            pack4(Ot[mt][0] * inv, Ot[mt][1] * inv, Ot[mt][2] * inv, Ot[mt][3] * inv);
}

// ---------------------------------------------------------------------------
extern "C" void kernel_launch(void* const* d_in, const int* in_sizes, int n_in,
                              void* d_out, int out_size, void* d_ws, size_t ws_size,
                              hipStream_t stream)
{
    const float* x   = (const float*)d_in[0];
    const float* Wq  = (const float*)d_in[1];
    const float* bq  = (const float*)d_in[2];
    const float* Wk  = (const float*)d_in[3];
    const float* bk  = (const float*)d_in[4];
    const float* Wv  = (const float*)d_in[5];
    const float* bv  = (const float*)d_in[6];
    const float* Wo  = (const float*)d_in[7];
    const float* bo  = (const float*)d_in[8];
    const float* J   = (const float*)d_in[9];
    const float* lam = (const float*)d_in[10];

    u16* ws  = (u16*)d_ws;
    u16* xb  = ws;                                   // 4096*1024 bf16 (reused as attn)
    u16* Wqb = xb  + (size_t)4096 * 1024;
    u16* Wkb = Wqb + (size_t)1024 * 1024;
    u16* Wvb = Wkb + (size_t)1024 * 1024;
    u16* Wob = Wvb + (size_t)1024 * 1024;
    u16* Qa  = Wob + (size_t)1024 * 1024;            // 32*2048*128
    u16* Ka  = Qa  + (size_t)32 * 2048 * 128;        // 32*2048*128
    u16* Vt  = Ka  + (size_t)32 * 2048 * 128;        // 32*64*2048 (b,h,d,s)
    u16* attn = xb;                                  // alias: xb dead after QKV
    float* dout = (float*)d_out;

    dim3 blk(256);
    // fp32 -> bf16 for x and the four weight matrices
    cvt_all<<<dim3(4096), blk, 0, stream>>>(x, Wq, Wk, Wv, Wo, ws);
    // fused Q/K/V projections
    gemm_epi<4><<<dim3(8, 32, 3), blk, 0, stream>>>(
        xb, Wqb, bq, Wkb, bk, Wvb, bv, lam, Qa, Ka, Vt, dout, 0);
    // Ka[:,64:128] = tanh(K) @ J_h^T
    ukern<<<dim3(32, 32), blk, 0, stream>>>(J, Ka);
    // causal flash attention, augmented 128-dim QK (balanced + XCD-local map)
    flash<<<dim3(256, 4), blk, 0, stream>>>(Qa, Ka, Vt, attn);
    // output projection (64-row tiles -> 512 blocks for occupancy)
    gemm_epi<2><<<dim3(8, 64, 1), blk, 0, stream>>>(
        attn, Wob, bo, Wob, bo, Wob, bo, lam, Qa, Ka, Vt, dout, 3);
}

// Round 6
// 210.770 us; speedup vs baseline: 1.8119x; 1.0203x over previous
//
#include <hip/hip_runtime.h>
#include <hip/hip_bf16.h>

typedef unsigned short u16;
typedef __bf16 bf16x8 __attribute__((ext_vector_type(8)));
typedef float f32x4 __attribute__((ext_vector_type(4)));
typedef unsigned short u16x4 __attribute__((ext_vector_type(4)));

#define MFMA16(a, b, c) __builtin_amdgcn_mfma_f32_16x16x32_bf16(a, b, c, 0, 0, 0)

#define EMB 1024
#define SEQ 2048
#define NH 16
#define HD 64
#define LOG2E 1.4426950408889634f

// async global->LDS, 16B per lane; LDS dest = wave-uniform base + lane*16
#define GLOAD_LDS16(g, l) __builtin_amdgcn_global_load_lds( \
    (const __attribute__((address_space(1))) unsigned int*)(g), \
    (__attribute__((address_space(3))) unsigned int*)(l), 16, 0, 0)

__device__ __forceinline__ float b2f(u16 u) {
    union { unsigned int i; float f; } v; v.i = ((unsigned int)u) << 16; return v.f;
}
__device__ __forceinline__ u16 f2b(float f) {
    __hip_bfloat16 h = __float2bfloat16(f);
    return *reinterpret_cast<u16*>(&h);
}
__device__ __forceinline__ u16x4 pack4(float a, float b, float c, float d) {
    union { __hip_bfloat162 h2[2]; u16x4 u; } r;
    r.h2[0] = __float22bfloat162_rn(float2{a, b});
    r.h2[1] = __float22bfloat162_rn(float2{c, d});
    return r.u;
}
__device__ __forceinline__ bf16x8 ldfrag(const u16* p) {
    return *reinterpret_cast<const bf16x8*>(p);
}
__device__ __forceinline__ bf16x8 cvt8(const float* p) {
    const float4 a = *reinterpret_cast<const float4*>(p);
    const float4 b = *reinterpret_cast<const float4*>(p + 4);
    union { u16x4 q[2]; bf16x8 v; } r;
    r.q[0] = pack4(a.x, a.y, a.z, a.w);
    r.q[1] = pack4(b.x, b.y, b.z, b.w);
    return r.v;
}
// tanh via hw exp2 + rcp: rel err < 1e-6, safe for |x| < 40
__device__ __forceinline__ float fast_tanh(float x) {
    float t = exp2f(x * (2.0f * LOG2E));
    return 1.0f - 2.0f * __builtin_amdgcn_rcpf(t + 1.0f);
}
__device__ __forceinline__ bf16x8 tanh8(bf16x8 v) {
    union { bf16x8 v; u16 u[8]; } in; in.v = v;
    float o[8];
#pragma unroll
    for (int e = 0; e < 8; e++) o[e] = fast_tanh(b2f(in.u[e]));
    union { u16x4 q[2]; bf16x8 v; } r;
    r.q[0] = pack4(o[0], o[1], o[2], o[3]);
    r.q[1] = pack4(o[4], o[5], o[6], o[7]);
    return r.v;
}

// ---------------------------------------------------------------------------
// fp32 -> bf16 conversion: [x (4096x1024) | Wq | Wk | Wv | Wo] -> ws bf16
// ---------------------------------------------------------------------------
__global__ __launch_bounds__(256) void cvt_all(
        const float* __restrict__ x,  const float* __restrict__ Wq,
        const float* __restrict__ Wk, const float* __restrict__ Wv,
        const float* __restrict__ Wo, u16* __restrict__ dst)
{
    size_t i = ((size_t)blockIdx.x * 256 + threadIdx.x) * 8;
    const float* src; size_t off;
    if (i < 4194304) { src = x; off = i; }
    else {
        size_t j = i - 4194304; int w = (int)(j >> 20); off = j & 1048575;
        src = (w == 0) ? Wq : (w == 1) ? Wk : (w == 2) ? Wv : Wo;
    }
    *(bf16x8*)&dst[i] = cvt8(src + off);
}

// ---------------------------------------------------------------------------
// GEMM: C = A(MxK,bf16) @ W(NxK,bf16)^T + bias(fp32). Tile MI*32 x 128, BK=64.
// 256 thr = 4 waves (2x2). global_load_lds staging, XOR chunk swizzle (8 chunks
// per 64-elem row: col8 = cc ^ (row&7) -> 2-way banks on frag reads = free).
// mode 0: Qa[:,0:64]=Q/8*log2e, Qa[:,64:128]=lam*log2e*tanh(Q) (B,H,S,128)
// mode 1: Ka[:,0:64]=K                                (B,H,S,128) bf16
// mode 2: Vt[b,h,d,s]=V  (transposed)                 (B,H,HD,S)  bf16
// mode 3: out = val fp32 (row-major M x EMB)
// ---------------------------------------------------------------------------
template<int MI>   // m-frags per wave (4 -> 128-row tile, 2 -> 64-row tile)
__global__ __launch_bounds__(256, 4) void gemm_epi(
        const u16* __restrict__ A,
        const u16* __restrict__ W0, const float* __restrict__ B0,
        const u16* __restrict__ W1, const float* __restrict__ B1,
        const u16* __restrict__ W2, const float* __restrict__ B2,
        const float* __restrict__ lam,
        u16* __restrict__ Qa, u16* __restrict__ Ka, u16* __restrict__ Vt,
        float* __restrict__ out, int modeBase)
{
    const int mode = modeBase + blockIdx.z;
    const u16* W; const float* bias;
    if (blockIdx.z == 0)      { W = W0; bias = B0; }
    else if (blockIdx.z == 1) { W = W1; bias = B1; }
    else                      { W = W2; bias = B2; }

    __shared__ __attribute__((aligned(16))) u16 sA[MI * 32 * 64];
    __shared__ __attribute__((aligned(16))) u16 sB[128 * 64];

    const int t = threadIdx.x;
    const int w = t >> 6, L = t & 63;
    const int wm = w >> 1, wn = w & 1;
    const int lr = L & 15, lq = L >> 4;
    const int wbase = t & 192;                   // wave*64
    const int m0 = blockIdx.y * (MI * 32), n0 = blockIdx.x * 128;

    f32x4 acc[MI][4];
#pragma unroll
    for (int i = 0; i < MI; i++)
#pragma unroll
        for (int j = 0; j < 4; j++) { f32x4 z = {0.f, 0.f, 0.f, 0.f}; acc[i][j] = z; }

    for (int k0 = 0; k0 < EMB; k0 += 64) {
        __syncthreads();
        // stage A: MI*256 chunks of 8 elems (8 chunks/row), col8 = cc ^ (row&7)
#pragma unroll
        for (int q = 0; q < MI; q++) {
            int c = q * 256 + t;
            int row = c >> 3, cc = c & 7;
            int col8 = cc ^ (row & 7);
            GLOAD_LDS16(&A[(size_t)(m0 + row) * EMB + k0 + col8 * 8],
                        &sA[(q * 256 + wbase) * 8]);
        }
        // stage B: 1024 chunks
#pragma unroll
        for (int q = 0; q < 4; q++) {
            int c = q * 256 + t;
            int row = c >> 3, cc = c & 7;
            int col8 = cc ^ (row & 7);
            GLOAD_LDS16(&W[(size_t)(n0 + row) * EMB + k0 + col8 * 8],
                        &sB[(q * 256 + wbase) * 8]);
        }
        __syncthreads();
        // two 32-k sub-chunks; fragments loaded per sub-chunk to bound VGPR
#pragma unroll
        for (int s = 0; s < 2; s++) {
            bf16x8 af[MI], bfr[4];
#pragma unroll
            for (int mi = 0; mi < MI; mi++) {
                int row = wm * (MI * 16) + mi * 16 + lr;
                af[mi] = ldfrag(&sA[(row * 8 + ((s * 4 + lq) ^ (row & 7))) * 8]);
            }
#pragma unroll
            for (int ni = 0; ni < 4; ni++) {
                int row = wn * 64 + ni * 16 + lr;
                bfr[ni] = ldfrag(&sB[(row * 8 + ((s * 4 + lq) ^ (row & 7))) * 8]);
            }
#pragma unroll
            for (int mi = 0; mi < MI; mi++)
#pragma unroll
                for (int ni = 0; ni < 4; ni++)
                    acc[mi][ni] = MFMA16(af[mi], bfr[ni], acc[mi][ni]);
        }
    }

    const float lamf = lam[0];
#pragma unroll
    for (int mi = 0; mi < MI; mi++)
#pragma unroll
        for (int ni = 0; ni < 4; ni++) {
            int mb = m0 + wm * (MI * 16) + mi * 16 + lq * 4;
            int n  = n0 + wn * 64 + ni * 16 + lr;
            float bv = bias[n];
            if (mode == 3) {
#pragma unroll
                for (int r = 0; r < 4; r++)
                    out[(size_t)(mb + r) * EMB + n] = acc[mi][ni][r] + bv;
            } else {
                int b = mb >> 11, s0 = mb & 2047;
                int h = n >> 6,  d = n & 63;
                if (mode == 0) {
#pragma unroll
                    for (int r = 0; r < 4; r++) {
                        float val = acc[mi][ni][r] + bv;
                        size_t i128 = ((size_t)(b * NH + h) * SEQ + s0 + r) * 128 + d;
                        Qa[i128]      = f2b(val * (0.125f * LOG2E));
                        Qa[i128 + 64] = f2b(lamf * LOG2E * fast_tanh(val));
                    }
                } else if (mode == 1) {
#pragma unroll
                    for (int r = 0; r < 4; r++) {
                        float val = acc[mi][ni][r] + bv;
                        Ka[((size_t)(b * NH + h) * SEQ + s0 + r) * 128 + d] = f2b(val);
                    }
                } else {
                    u16x4 pk = pack4(acc[mi][ni][0] + bv, acc[mi][ni][1] + bv,
                                     acc[mi][ni][2] + bv, acc[mi][ni][3] + bv);
                    *(u16x4*)&Vt[((size_t)(b * NH + h) * HD + d) * SEQ + s0] = pk;
                }
            }
        }
}

// ---------------------------------------------------------------------------
// U kernel: Ka[:,64:128] = tanh(K) @ J_h^T per (b,h); K read from Ka[:,0:64]
// grid: (S/64, B*H), 256 threads
// ---------------------------------------------------------------------------
__global__ __launch_bounds__(256) void ukern(
        const float* __restrict__ J, u16* __restrict__ Ka)
{
    __shared__ __attribute__((aligned(16))) u16 sJ[64 * 72];
    const int t = threadIdx.x, w = t >> 6, L = t & 63, lr = L & 15, lq = L >> 4;
    const int rt = blockIdx.x, bh = blockIdx.y, h = bh & 15;

#pragma unroll
    for (int i = 0; i < 2; i++) {
        int c = t + 256 * i;
        int row = c >> 3, col = (c & 7) * 8;
        *(bf16x8*)&sJ[row * 72 + col] = cvt8(&J[(size_t)h * 4096 + row * 64 + col]);
    }
    __syncthreads();

    const u16* krow = &Ka[((size_t)bh * SEQ + rt * 64 + w * 16 + lr) * 128];
    bf16x8 a0 = tanh8(ldfrag(krow + lq * 8));
    bf16x8 a1 = tanh8(ldfrag(krow + lq * 8 + 32));
#pragma unroll
    for (int nt = 0; nt < 4; nt++) {
        f32x4 acc = {0.f, 0.f, 0.f, 0.f};
        acc = MFMA16(a0, ldfrag(&sJ[(nt * 16 + lr) * 72 + lq * 8]), acc);
        acc = MFMA16(a1, ldfrag(&sJ[(nt * 16 + lr) * 72 + lq * 8 + 32]), acc);
#pragma unroll
        for (int r = 0; r < 4; r++) {
            int j = rt * 64 + w * 16 + lq * 4 + r;
            Ka[((size_t)bh * SEQ + j) * 128 + 64 + nt * 16 + lr] = f2b(acc[r]);
        }
    }
}

// ---------------------------------------------------------------------------
// Causal flash, S^T formulation, BM=128: each wave holds TWO 16-row Q B-operand
// sets in regs, so every K/V A-fragment read from LDS feeds 2 MFMAs (halves
// LDS read per FLOP — the prior BW floor). No-max softmax (scores bounded).
// grid: (256, 2): bh = bx&31 (XCD-local), p = bx>>5; qt = by? 15-p : p
//   -> round-robin pair on each CU sums to 34 iters (balanced).
// ---------------------------------------------------------------------------
__global__ __launch_bounds__(256) void flash(
        const u16* __restrict__ Qa, const u16* __restrict__ Ka,
        const u16* __restrict__ Vt, u16* __restrict__ attn)
{
    __shared__ __attribute__((aligned(16))) u16 sK[64 * 128];   // swizzled chunks
    __shared__ __attribute__((aligned(16))) u16 sVt[64 * 64];   // swizzled chunks
    __shared__ __attribute__((aligned(16))) u16 sP[128 * 72];   // padded rows

    const int t = threadIdx.x, w = t >> 6, L = t & 63, lr = L & 15, lq = L >> 4;
    const int bh = blockIdx.x & 31, p = blockIdx.x >> 5;
    const int qt = blockIdx.y ? 15 - p : p;
    const int qm = qt * 128;
    const int i_l = w * 16 + lr;            // lane's q-row within a 64-set
    const int wbase = t & 192;
    const u16* Kbase = Ka + (size_t)bh * SEQ * 128;
    const u16* Vbase = Vt + (size_t)bh * HD * SEQ;

    // two Q B-operand sets: set g covers q-rows qm + g*64 + [0,64)
    bf16x8 qf[2][4];
#pragma unroll
    for (int g = 0; g < 2; g++) {
        const u16* qrow = Qa + ((size_t)bh * SEQ + qm + g * 64 + i_l) * 128;
#pragma unroll
        for (int s = 0; s < 4; s++) qf[g][s] = ldfrag(qrow + s * 32 + lq * 8);
    }

    f32x4 Ot[2][4];
#pragma unroll
    for (int g = 0; g < 2; g++)
#pragma unroll
        for (int i = 0; i < 4; i++) { f32x4 z = {0.f, 0.f, 0.f, 0.f}; Ot[g][i] = z; }
    float lsum[2] = {0.f, 0.f};

    const int ktmax = 2 * qt + 1;
    for (int kt = 0; kt <= ktmax; kt++) {
        const int kn = kt * 64;
        __syncthreads();
        // stage K tile 64x128: 1024 chunks, swizzle col8 = cc ^ (row&15)
#pragma unroll
        for (int q = 0; q < 4; q++) {
            int cch = q * 256 + t;
            int row = cch >> 4, cc = cch & 15;
            int col8 = cc ^ (row & 15);
            GLOAD_LDS16(&Kbase[(size_t)(kn + row) * 128 + col8 * 8],
                        &sK[(q * 256 + wbase) * 8]);
        }
        // stage V^T tile 64x64: 512 chunks, swizzle j8 = cc ^ (d&7)
#pragma unroll
        for (int q = 0; q < 2; q++) {
            int cch = q * 256 + t;
            int d = cch >> 3, cc = cch & 7;
            int j8 = cc ^ (d & 7);
            GLOAD_LDS16(&Vbase[(size_t)d * SEQ + kn + j8 * 8],
                        &sVt[(q * 256 + wbase) * 8]);
        }
        __syncthreads();

        // S^T: each K-fragment feeds both Q sets
        f32x4 sc[2][4];
#pragma unroll
        for (int g = 0; g < 2; g++)
#pragma unroll
            for (int mt = 0; mt < 4; mt++) { f32x4 z = {0.f,0.f,0.f,0.f}; sc[g][mt] = z; }
#pragma unroll
        for (int mt = 0; mt < 4; mt++) {
            int j = mt * 16 + lr;
#pragma unroll
            for (int s = 0; s < 4; s++) {
                bf16x8 kf = ldfrag(&sK[(j * 16 + ((s * 4 + lq) ^ (j & 15))) * 8]);
                sc[0][mt] = MFMA16(kf, qf[0][s], sc[0][mt]);
                sc[1][mt] = MFMA16(kf, qf[1][s], sc[1][mt]);
            }
        }
        // causal masks only on the last two k-tiles
        if (kt >= ktmax - 1) {
            const int thr0 = (kt == ktmax) ? -1  : i_l;
            const int thr1 = (kt == ktmax) ? i_l : 63;
#pragma unroll
            for (int mt = 0; mt < 4; mt++)
#pragma unroll
                for (int r = 0; r < 4; r++) {
                    int j = mt * 16 + lq * 4 + r;
                    if (j > thr0) sc[0][mt][r] = -INFINITY;
                    if (j > thr1) sc[1][mt][r] = -INFINITY;
                }
        }
        // no-max softmax: P = exp2(s); per-lane partial sums
#pragma unroll
        for (int g = 0; g < 2; g++) {
#pragma unroll
            for (int mt = 0; mt < 4; mt++)
#pragma unroll
                for (int r = 0; r < 4; r++) {
                    float e = exp2f(sc[g][mt][r]);
                    sc[g][mt][r] = e;
                    lsum[g] += e;
                }
#pragma unroll
            for (int mt = 0; mt < 4; mt++)
                *(u16x4*)&sP[(g * 64 + i_l) * 72 + mt * 16 + lq * 4] =
                    pack4(sc[g][mt][0], sc[g][mt][1], sc[g][mt][2], sc[g][mt][3]);
        }
        // O^T += V^T @ P^T: each V-fragment feeds both P sets
#pragma unroll
        for (int s2 = 0; s2 < 2; s2++) {
            bf16x8 pf0 = ldfrag(&sP[(i_l) * 72 + s2 * 32 + lq * 8]);
            bf16x8 pf1 = ldfrag(&sP[(64 + i_l) * 72 + s2 * 32 + lq * 8]);
#pragma unroll
            for (int mt = 0; mt < 4; mt++) {
                int d = mt * 16 + lr;
                bf16x8 vf = ldfrag(&sVt[(d * 8 + ((s2 * 4 + lq) ^ (d & 7))) * 8]);
                Ot[0][mt] = MFMA16(vf, pf0, Ot[0][mt]);
                Ot[1][mt] = MFMA16(vf, pf1, Ot[1][mt]);
            }
        }
    }

    const int b = bh >> 4, h = bh & 15;
#pragma unroll
    for (int g = 0; g < 2; g++) {
        float ls = lsum[g];
        ls += __shfl_xor(ls, 16);
        ls += __shfl_xor(ls, 32);
        const float r0 = __builtin_amdgcn_rcpf(ls);
        const float inv = r0 * (2.0f - ls * r0);  // NR refine
        const size_t base = ((size_t)(b * SEQ + qm + g * 64 + i_l)) * EMB + h * HD;
#pragma unroll
        for (int mt = 0; mt < 4; mt++)
            *(u16x4*)&attn[base + mt * 16 + lq * 4] =
                pack4(Ot[g][mt][0] * inv, Ot[g][mt][1] * inv,
                      Ot[g][mt][2] * inv, Ot[g][mt][3] * inv);
    }
}

// ---------------------------------------------------------------------------
extern "C" void kernel_launch(void* const* d_in, const int* in_sizes, int n_in,
                              void* d_out, int out_size, void* d_ws, size_t ws_size,
                              hipStream_t stream)
{
    const float* x   = (const float*)d_in[0];
    const float* Wq  = (const float*)d_in[1];
    const float* bq  = (const float*)d_in[2];
    const float* Wk  = (const float*)d_in[3];
    const float* bk  = (const float*)d_in[4];
    const float* Wv  = (const float*)d_in[5];
    const float* bv  = (const float*)d_in[6];
    const float* Wo  = (const float*)d_in[7];
    const float* bo  = (const float*)d_in[8];
    const float* J   = (const float*)d_in[9];
    const float* lam = (const float*)d_in[10];

    u16* ws  = (u16*)d_ws;
    u16* xb  = ws;                                   // 4096*1024 bf16 (reused as attn)
    u16* Wqb = xb  + (size_t)4096 * 1024;
    u16* Wkb = Wqb + (size_t)1024 * 1024;
    u16* Wvb = Wkb + (size_t)1024 * 1024;
    u16* Wob = Wvb + (size_t)1024 * 1024;
    u16* Qa  = Wob + (size_t)1024 * 1024;            // 32*2048*128
    u16* Ka  = Qa  + (size_t)32 * 2048 * 128;        // 32*2048*128
    u16* Vt  = Ka  + (size_t)32 * 2048 * 128;        // 32*64*2048 (b,h,d,s)
    u16* attn = xb;                                  // alias: xb dead after QKV
    float* dout = (float*)d_out;

    dim3 blk(256);
    // fp32 -> bf16 for x and the four weight matrices
    cvt_all<<<dim3(4096), blk, 0, stream>>>(x, Wq, Wk, Wv, Wo, ws);
    // fused Q/K/V projections (BK=64)
    gemm_epi<4><<<dim3(8, 32, 3), blk, 0, stream>>>(
        xb, Wqb, bq, Wkb, bk, Wvb, bv, lam, Qa, Ka, Vt, dout, 0);
    // Ka[:,64:128] = tanh(K) @ J_h^T
    ukern<<<dim3(32, 32), blk, 0, stream>>>(J, Ka);
    // causal flash attention, BM=128, augmented 128-dim QK
    flash<<<dim3(256, 2), blk, 0, stream>>>(Qa, Ka, Vt, attn);
    // output projection (64-row tiles -> 512 blocks for occupancy)
    gemm_epi<2><<<dim3(8, 64, 1), blk, 0, stream>>>(
        attn, Wob, bo, Wob, bo, Wob, bo, lam, Qa, Ka, Vt, dout, 3);
}